// Round 9
// baseline (349.791 us; speedup 1.0000x reference)
//
#include <hip/hip_runtime.h>
#include <stdint.h>

#define N_Q 16384
#define M_P 1024
#define D_K 1024

typedef __attribute__((ext_vector_type(8))) __bf16 bf16x8;
typedef __attribute__((ext_vector_type(4))) float floatx4;

#define AS1 __attribute__((address_space(1)))
#define AS3 __attribute__((address_space(3)))

__device__ __forceinline__ unsigned short f2bf(float f) {
    unsigned int u = __float_as_uint(f);
    u += 0x7fffu + ((u >> 16) & 1u);   // round-to-nearest-even
    return (unsigned short)(u >> 16);
}
__device__ __forceinline__ float bf2f(unsigned short h) {
    return __uint_as_float(((unsigned int)h) << 16);
}

// In-register fp32 -> bf16 hi/lo split (trunc-hi; lo captures the residual).
__device__ __forceinline__ void split8(floatx4 f0, floatx4 f1,
                                       bf16x8* ah, bf16x8* al) {
    union { bf16x8 v; unsigned short s[8]; } H, L;
    float e[8] = {f0.x, f0.y, f0.z, f0.w, f1.x, f1.y, f1.z, f1.w};
#pragma unroll
    for (int j = 0; j < 8; ++j) {
        unsigned int u = __float_as_uint(e[j]);
        H.s[j] = (unsigned short)(u >> 16);
        float lo = e[j] - __uint_as_float(u & 0xffff0000u);
        L.s[j] = (unsigned short)(__float_as_uint(lo) >> 16);
    }
    *ah = H.v;
    *al = L.v;
}

// ---------------------------------------------------------------------------
// Proto convert: split fp32 -> bf16 hi/lo + p2[m]; blocks 0..127 also zero
// the per-strip finisher counters (d_ws is poisoned 0xAA before each launch).
// ---------------------------------------------------------------------------
__global__ __launch_bounds__(256) void convert_proto_kernel(
    const float* __restrict__ proto, unsigned short* __restrict__ ph,
    unsigned short* __restrict__ pl, float* __restrict__ p2,
    int* __restrict__ cnt) {
    __shared__ float sred[4];
    int m = blockIdx.x;
    int t = threadIdx.x;
    if (t == 0 && m < 128) cnt[m] = 0;
    size_t base4 = (size_t)m * (D_K / 4) + t;
    float4 v = ((const float4*)proto)[base4];
    ushort4 h, l;
    h.x = f2bf(v.x); l.x = f2bf(v.x - bf2f(h.x));
    h.y = f2bf(v.y); l.y = f2bf(v.y - bf2f(h.y));
    h.z = f2bf(v.z); l.z = f2bf(v.z - bf2f(h.z));
    h.w = f2bf(v.w); l.w = f2bf(v.w - bf2f(h.w));
    ((ushort4*)ph)[base4] = h;
    ((ushort4*)pl)[base4] = l;
    float sq = v.x * v.x + v.y * v.y + v.z * v.z + v.w * v.w;
#pragma unroll
    for (int off = 1; off < 64; off <<= 1) sq += __shfl_xor(sq, off);
    if ((t & 63) == 0) sred[t >> 6] = sq;
    __syncthreads();
    if (t == 0) p2[m] = sred[0] + sred[1] + sred[2] + sred[3];
}

// ---------------------------------------------------------------------------
// GEMM + last-block fused softmax.
// logits[n,m] = 2*sum_d q[n,d]*p[m,d] - p2[m]; A (query) staged RAW FP32 into
// LDS, split to bf16 hi/lo in VGPRs; B (proto) pre-split. 128x128 tile,
// 2 waves, wave-tile 64x128, 3-term MFMA (drop ql*pl).
//
// XCD-aware grid: b%8 == nt&7 -> all 8 mt-blocks of an nt-strip land on one
// XCD (R7: FETCH halved), finish near-simultaneously, strip logits (512KB)
// stay hot in that XCD's 4MB L2. The 8th finisher (device-scope atomicAdd +
// threadfence, G16 pattern) re-reads the strip from L2 and does wave-per-row
// softmax in place -> the separate softmax dispatch and most of its 192MiB
// HBM round-trip disappear. Non-finishers exit (no spin -> no deadlock).
// ---------------------------------------------------------------------------
__global__ __launch_bounds__(128, 2) void gemm_logits_kernel(
    const float* __restrict__ query,
    const unsigned short* __restrict__ ph, const unsigned short* __restrict__ pl,
    const float* __restrict__ p2, float* __restrict__ out,
    int* __restrict__ cnt) {
    __shared__ float sAf[128 * 32];             // 16 KB fp32 A tile
    __shared__ unsigned short sBh[128 * 32];    // 8 KB
    __shared__ unsigned short sBl[128 * 32];    // 8 KB
    __shared__ int amlast;

    const int tid = threadIdx.x;
    const int wave = tid >> 6;   // 0,1
    const int lane = tid & 63;
    const int b = blockIdx.x;
    const int mt = (b >> 3) & 7;
    const int nt = (b & 7) | ((b >> 6) << 3);
    const int row0 = nt * 128;
    const int col0 = mt * 128;

    // B staging mapping (R4-verified): quad-coalesced + XOR swizzle.
    const int rlB = lane >> 2;
    const int cioB = (lane & 3) ^ ((lane >> 3) & 3);
    const size_t laneoffB = (size_t)rlB * D_K + cioB * 8;
    const unsigned short* gBh = ph + (size_t)col0 * D_K + laneoffB;
    const unsigned short* gBl = pl + (size_t)col0 * D_K + laneoffB;

    // A staging mapping: 8 rows/inst, granule XOR within the row's 128B.
    const int rlA = lane >> 3;                  // 0..7
    const int cioA = (lane & 7) ^ rlA;          // 16B granule in row
    const float* gA = query + (size_t)(row0 + rlA) * D_K + cioA * 4;

    floatx4 zero = {0.0f, 0.0f, 0.0f, 0.0f};
    floatx4 acc[4][8];
#pragma unroll
    for (int i = 0; i < 4; ++i)
#pragma unroll
        for (int j = 0; j < 8; ++j) acc[i][j] = zero;

    const int rsel = lane & 15;
    const int kq = lane >> 4;
    const int gswB = 4 * rsel + (kq ^ ((rsel >> 1) & 3));
    const int fragoffB = gswB * 8;  // shorts
    const int pA0 = rsel * 8 + ((2 * kq) ^ (rsel & 7));
    const int pA1 = rsel * 8 + ((2 * kq + 1) ^ (rsel & 7));

    for (int kt = 0; kt < D_K / 32; ++kt) {
        const int kbase = kt * 32;
        if (wave == 0) {
#pragma unroll
            for (int s = 0; s < 8; ++s)
#pragma unroll
                for (int t = 0; t < 2; ++t)
                    __builtin_amdgcn_global_load_lds(
                        (const AS1 unsigned int*)(const void*)(gA + (size_t)(s * 16 + t * 8) * D_K + kbase),
                        (AS3 unsigned int*)(void*)(sAf + s * 512 + t * 256), 16, 0, 0);
        } else {
#pragma unroll
            for (int s = 0; s < 8; ++s) {
                const size_t go = (size_t)(s * 16) * D_K + kbase;
                __builtin_amdgcn_global_load_lds(
                    (const AS1 unsigned int*)(const void*)(gBh + go),
                    (AS3 unsigned int*)(void*)(sBh + s * 512), 16, 0, 0);
                __builtin_amdgcn_global_load_lds(
                    (const AS1 unsigned int*)(const void*)(gBl + go),
                    (AS3 unsigned int*)(void*)(sBl + s * 512), 16, 0, 0);
            }
        }
        __syncthreads();

        bf16x8 ah[4], al[4];
#pragma unroll
        for (int i = 0; i < 4; ++i) {
            const int st = wave * 4 + i;
            floatx4 f0 = *(const floatx4*)(sAf + st * 512 + pA0 * 4);
            floatx4 f1 = *(const floatx4*)(sAf + st * 512 + pA1 * 4);
            split8(f0, f1, &ah[i], &al[i]);
        }
#pragma unroll
        for (int j = 0; j < 8; ++j) {
            const int boff = j * 512 + fragoffB;
            bf16x8 bhj = *(const bf16x8*)(sBh + boff);
            bf16x8 blj = *(const bf16x8*)(sBl + boff);
#pragma unroll
            for (int i = 0; i < 4; ++i) {
                acc[i][j] = __builtin_amdgcn_mfma_f32_16x16x32_bf16(ah[i], bhj, acc[i][j], 0, 0, 0);
                acc[i][j] = __builtin_amdgcn_mfma_f32_16x16x32_bf16(ah[i], blj, acc[i][j], 0, 0, 0);
                acc[i][j] = __builtin_amdgcn_mfma_f32_16x16x32_bf16(al[i], bhj, acc[i][j], 0, 0, 0);
            }
        }
        __syncthreads();
    }

    // ---- epilogue: store logits = 2*qp - p2[col] ----
    // C layout (verified m89/m91): col = lane&15, row = (lane>>4)*4 + reg
#pragma unroll
    for (int j = 0; j < 8; ++j) {
        const int gc = col0 + j * 16 + rsel;
        const float p2v = p2[gc];
#pragma unroll
        for (int i = 0; i < 4; ++i) {
            const int gr = row0 + wave * 64 + i * 16 + kq * 4;
#pragma unroll
            for (int r = 0; r < 4; ++r) {
                out[(size_t)(gr + r) * M_P + gc] = 2.0f * acc[i][j][r] - p2v;
            }
        }
    }

    // ---- last-block fused softmax for this nt-strip ----
    __threadfence();                 // release: logits visible device-wide
    if (tid == 0) {
        int prev = atomicAdd(&cnt[nt], 1);
        amlast = (prev == 7) ? 1 : 0;
    }
    __syncthreads();
    if (!amlast) return;
    __threadfence();                 // acquire: other blocks' logits visible

    // wave w handles rows row0 + w*64 + [0,64), two rows per iter for ILP.
    float* base = out + (size_t)(row0 + wave * 64) * M_P;
    for (int rr = 0; rr < 64; rr += 2) {
        float* r0 = base + (size_t)rr * M_P;
        float* r1 = r0 + M_P;
        floatx4 va[4], vb[4];
#pragma unroll
        for (int k = 0; k < 4; ++k) {
            va[k] = *((const floatx4*)r0 + k * 64 + lane);
            vb[k] = *((const floatx4*)r1 + k * 64 + lane);
        }
        float ma = fmaxf(fmaxf(va[0].x, va[0].y), fmaxf(va[0].z, va[0].w));
        float mb = fmaxf(fmaxf(vb[0].x, vb[0].y), fmaxf(vb[0].z, vb[0].w));
#pragma unroll
        for (int k = 1; k < 4; ++k) {
            ma = fmaxf(ma, fmaxf(fmaxf(va[k].x, va[k].y), fmaxf(va[k].z, va[k].w)));
            mb = fmaxf(mb, fmaxf(fmaxf(vb[k].x, vb[k].y), fmaxf(vb[k].z, vb[k].w)));
        }
#pragma unroll
        for (int off = 1; off < 64; off <<= 1) {
            ma = fmaxf(ma, __shfl_xor(ma, off));
            mb = fmaxf(mb, __shfl_xor(mb, off));
        }
        float sa = 0.0f, sb = 0.0f;
#pragma unroll
        for (int k = 0; k < 4; ++k) {
            va[k].x = __expf(va[k].x - ma); va[k].y = __expf(va[k].y - ma);
            va[k].z = __expf(va[k].z - ma); va[k].w = __expf(va[k].w - ma);
            sa += va[k].x + va[k].y + va[k].z + va[k].w;
            vb[k].x = __expf(vb[k].x - mb); vb[k].y = __expf(vb[k].y - mb);
            vb[k].z = __expf(vb[k].z - mb); vb[k].w = __expf(vb[k].w - mb);
            sb += vb[k].x + vb[k].y + vb[k].z + vb[k].w;
        }
#pragma unroll
        for (int off = 1; off < 64; off <<= 1) {
            sa += __shfl_xor(sa, off);
            sb += __shfl_xor(sb, off);
        }
        const float ia = 1.0f / sa, ib = 1.0f / sb;
#pragma unroll
        for (int k = 0; k < 4; ++k) {
            floatx4 oa, ob;
            oa.x = va[k].x * ia; oa.y = va[k].y * ia;
            oa.z = va[k].z * ia; oa.w = va[k].w * ia;
            ob.x = vb[k].x * ib; ob.y = vb[k].y * ib;
            ob.z = vb[k].z * ib; ob.w = vb[k].w * ib;
            __builtin_nontemporal_store(oa, (floatx4*)r0 + k * 64 + lane);
            __builtin_nontemporal_store(ob, (floatx4*)r1 + k * 64 + lane);
        }
    }
}

// ---------------------------------------------------------------------------
// Fallback (tiny workspace): naive fp32 logits + separate softmax.
// ---------------------------------------------------------------------------
__global__ __launch_bounds__(256) void naive_logits_kernel(
    const float* __restrict__ query, const float* __restrict__ proto,
    float* __restrict__ out) {
    __shared__ float qs[D_K];
    int n = blockIdx.x;
    int t = threadIdx.x;
    ((float4*)qs)[t] = ((const float4*)(query + (size_t)n * D_K))[t];
    __syncthreads();
    float acc[4] = {0.f, 0.f, 0.f, 0.f};
    float pp[4] = {0.f, 0.f, 0.f, 0.f};
    for (int d = 0; d < D_K; d += 4) {
        float4 qv = *(const float4*)(qs + d);
#pragma unroll
        for (int j = 0; j < 4; ++j) {
            const float4 pv = *(const float4*)(proto + (size_t)(t + 256 * j) * D_K + d);
            acc[j] += qv.x * pv.x + qv.y * pv.y + qv.z * pv.z + qv.w * pv.w;
            pp[j] += pv.x * pv.x + pv.y * pv.y + pv.z * pv.z + pv.w * pv.w;
        }
    }
#pragma unroll
    for (int j = 0; j < 4; ++j)
        out[(size_t)n * M_P + t + 256 * j] = 2.0f * acc[j] - pp[j];
}

__global__ __launch_bounds__(256) void softmax_kernel(float* __restrict__ out) {
    const int lane = threadIdx.x & 63;
    int n = blockIdx.x * 4 + (threadIdx.x >> 6);
    for (int it = 0; it < 2; ++it, n += 8192) {
        float* row = out + (size_t)n * M_P;
        floatx4 v[4];
#pragma unroll
        for (int k = 0; k < 4; ++k)
            v[k] = *((const floatx4*)(row + k * 256) + lane);
        float mx = fmaxf(fmaxf(v[0].x, v[0].y), fmaxf(v[0].z, v[0].w));
#pragma unroll
        for (int k = 1; k < 4; ++k)
            mx = fmaxf(mx, fmaxf(fmaxf(v[k].x, v[k].y), fmaxf(v[k].z, v[k].w)));
#pragma unroll
        for (int off = 1; off < 64; off <<= 1) mx = fmaxf(mx, __shfl_xor(mx, off));
        float s = 0.0f;
#pragma unroll
        for (int k = 0; k < 4; ++k) {
            v[k].x = __expf(v[k].x - mx);
            v[k].y = __expf(v[k].y - mx);
            v[k].z = __expf(v[k].z - mx);
            v[k].w = __expf(v[k].w - mx);
            s += v[k].x + v[k].y + v[k].z + v[k].w;
        }
#pragma unroll
        for (int off = 1; off < 64; off <<= 1) s += __shfl_xor(s, off);
        const float inv = 1.0f / s;
#pragma unroll
        for (int k = 0; k < 4; ++k) {
            floatx4 o;
            o.x = v[k].x * inv; o.y = v[k].y * inv;
            o.z = v[k].z * inv; o.w = v[k].w * inv;
            __builtin_nontemporal_store(o, (floatx4*)(row + k * 256) + lane);
        }
    }
}

extern "C" void kernel_launch(void* const* d_in, const int* in_sizes, int n_in,
                              void* d_out, int out_size, void* d_ws, size_t ws_size,
                              hipStream_t stream) {
    const float* query = (const float*)d_in[0];
    const float* proto = (const float*)d_in[1];
    float* out = (float*)d_out;

    const size_t pElems = (size_t)M_P * D_K;   // 1M
    const size_t needed = pElems * 2 * 2 + M_P * 4 + 128 * 4;  // ~4.2 MiB

    if (ws_size >= needed) {
        unsigned short* ph = (unsigned short*)d_ws;
        unsigned short* pl = ph + pElems;
        float* p2 = (float*)(pl + pElems);
        int* cnt = (int*)(p2 + M_P);

        convert_proto_kernel<<<M_P, 256, 0, stream>>>(proto, ph, pl, p2, cnt);
        gemm_logits_kernel<<<(N_Q / 128) * (M_P / 128), 128, 0, stream>>>(
            query, ph, pl, p2, out, cnt);
    } else {
        naive_logits_kernel<<<N_Q, 256, 0, stream>>>(query, proto, out);
        softmax_kernel<<<2048, 256, 0, stream>>>(out);
    }
}

// Round 10
// 212.900 us; speedup vs baseline: 1.6430x; 1.6430x over previous
//
#include <hip/hip_runtime.h>
#include <stdint.h>

#define N_Q 16384
#define M_P 1024
#define D_K 1024

typedef __attribute__((ext_vector_type(8))) __bf16 bf16x8;
typedef __attribute__((ext_vector_type(4))) float floatx4;
typedef __attribute__((ext_vector_type(4))) unsigned int uint4v;

#define AS1 __attribute__((address_space(1)))
#define AS3 __attribute__((address_space(3)))

__device__ __forceinline__ unsigned short f2bf(float f) {
    unsigned int u = __float_as_uint(f);
    u += 0x7fffu + ((u >> 16) & 1u);   // round-to-nearest-even
    return (unsigned short)(u >> 16);
}
__device__ __forceinline__ float bf2f(unsigned short h) {
    return __uint_as_float(((unsigned int)h) << 16);
}

// Split 8 fp32 (one k-chunk) -> packed bf16 hi (16B) + lo (16B).
// v_perm packs two hi-halves per instruction; trunc-hi + residual-lo
// (total rel err ~2^-16 per element -> logit err ~1e-3).
__device__ __forceinline__ void split_chunk(floatx4 f0, floatx4 f1,
                                            uint4v* hi, uint4v* lo) {
    float e[8] = {f0.x, f0.y, f0.z, f0.w, f1.x, f1.y, f1.z, f1.w};
    unsigned int hb[4], lb[4];
#pragma unroll
    for (int p = 0; p < 4; ++p) {
        unsigned int u0 = __float_as_uint(e[2 * p]);
        unsigned int u1 = __float_as_uint(e[2 * p + 1]);
        hb[p] = __builtin_amdgcn_perm(u1, u0, 0x07060302);  // [u0>>16, u1>>16]
        float l0 = e[2 * p]     - __uint_as_float(u0 & 0xffff0000u);
        float l1 = e[2 * p + 1] - __uint_as_float(u1 & 0xffff0000u);
        lb[p] = __builtin_amdgcn_perm(__float_as_uint(l1), __float_as_uint(l0),
                                      0x07060302);
    }
    uint4v h = {hb[0], hb[1], hb[2], hb[3]};
    uint4v l = {lb[0], lb[1], lb[2], lb[3]};
    *hi = h;
    *lo = l;
}

// ---------------------------------------------------------------------------
// Proto convert: split fp32 -> bf16 hi/lo + p2[m]. One block per row. ~5 us.
// ---------------------------------------------------------------------------
__global__ __launch_bounds__(256) void convert_proto_kernel(
    const float* __restrict__ proto, unsigned short* __restrict__ ph,
    unsigned short* __restrict__ pl, float* __restrict__ p2) {
    __shared__ float sred[4];
    int m = blockIdx.x;
    int t = threadIdx.x;
    size_t base4 = (size_t)m * (D_K / 4) + t;
    float4 v = ((const float4*)proto)[base4];
    ushort4 h, l;
    h.x = f2bf(v.x); l.x = f2bf(v.x - bf2f(h.x));
    h.y = f2bf(v.y); l.y = f2bf(v.y - bf2f(h.y));
    h.z = f2bf(v.z); l.z = f2bf(v.z - bf2f(h.z));
    h.w = f2bf(v.w); l.w = f2bf(v.w - bf2f(h.w));
    ((ushort4*)ph)[base4] = h;
    ((ushort4*)pl)[base4] = l;
    float sq = v.x * v.x + v.y * v.y + v.z * v.z + v.w * v.w;
#pragma unroll
    for (int off = 1; off < 64; off <<= 1) sq += __shfl_xor(sq, off);
    if ((t & 63) == 0) sred[t >> 6] = sq;
    __syncthreads();
    if (t == 0) p2[m] = sred[0] + sred[1] + sred[2] + sred[3];
}

// ---------------------------------------------------------------------------
// GEMM: logits[n,m] = 2*sum_d q[n,d]*p[m,d] - p2[m], bf16 hi/lo 3-term.
// 128x128 tile, 2 waves, wave-tile 64x128 (R7 compute structure, measured
// 102.5us / MfmaUtil 43.6%).
//
// A (query) is read as RAW FP32 with regular coalesced loads (each quad's
// two loads cover one 128B line), split to bf16 hi/lo in VGPRs DURING THE
// STAGING PHASE (overlaps vmcnt waits, m114), and ds_write_b128'd into the
// R7 swizzled layout (write set = bijection over all 64 granules ->
// conflict-free). R8 put the split on the ds_read->MFMA critical path and
// lost 10 pts of MfmaUtil; R9's L2-resident finisher softmax doubled
// WRITE_SIZE and serialized on a 128-block tail -> both reverted.
// B (proto) pre-split, async global_load_lds, R4-verified swizzle.
// XCD-aware grid: blocks 8 apart share nt (R7: FETCH halved).
// ---------------------------------------------------------------------------
__global__ __launch_bounds__(128, 2) void gemm_logits_kernel(
    const float* __restrict__ query,
    const unsigned short* __restrict__ ph, const unsigned short* __restrict__ pl,
    const float* __restrict__ p2, float* __restrict__ out) {
    __shared__ unsigned short sAh[128 * 32];    // 8 KB
    __shared__ unsigned short sAl[128 * 32];    // 8 KB
    __shared__ unsigned short sBh[128 * 32];    // 8 KB
    __shared__ unsigned short sBl[128 * 32];    // 8 KB

    const int tid = threadIdx.x;
    const int wave = tid >> 6;   // 0,1
    const int lane = tid & 63;
    const int b = blockIdx.x;
    const int mt = (b >> 3) & 7;
    const int nt = (b & 7) | ((b >> 6) << 3);
    const int row0 = nt * 128;
    const int col0 = mt * 128;

    // B staging (R4-verified): quad-coalesced + XOR swizzle; wave0 -> hi,
    // wave1 -> lo, 8 insts each.
    const int rlB = lane >> 2;
    const int cioB = (lane & 3) ^ ((lane >> 3) & 3);
    const size_t laneoffB = (size_t)rlB * D_K + cioB * 8;
    const unsigned short* gB =
        ((wave == 0) ? ph : pl) + (size_t)col0 * D_K + laneoffB;
    unsigned short* dstB = (wave == 0) ? sBh : sBl;

    // A staging: lane handles (row = l>>2 within subtile, chunk c = l&3);
    // loads f0 = granule 2c, f1 = granule 2c+1 (same 128B line per quad).
    const int rlA = lane >> 2;          // 0..15
    const int cA = lane & 3;            // k-chunk 0..3
    const float* gA = query + (size_t)(row0 + wave * 64 + rlA) * D_K + cA * 8;
    // swizzled granule position for (rlA, cA) -- same formula as compute side
    const int pw = 4 * rlA + (cA ^ ((rlA >> 1) & 3));
    const int wroff = pw * 8;           // shorts within subtile

    floatx4 zero = {0.0f, 0.0f, 0.0f, 0.0f};
    floatx4 acc[4][8];
#pragma unroll
    for (int i = 0; i < 4; ++i)
#pragma unroll
        for (int j = 0; j < 8; ++j) acc[i][j] = zero;

    const int rsel = lane & 15;
    const int kq = lane >> 4;
    const int gsw = 4 * rsel + (kq ^ ((rsel >> 1) & 3));
    const int fragoff = gsw * 8;  // shorts

    for (int kt = 0; kt < D_K / 32; ++kt) {
        const int kbase = kt * 32;
        // ---- B: async global->LDS (issue first, drains at barrier) ----
#pragma unroll
        for (int s = 0; s < 8; ++s)
            __builtin_amdgcn_global_load_lds(
                (const AS1 unsigned int*)(const void*)(gB + (size_t)(s * 16) * D_K + kbase),
                (AS3 unsigned int*)(void*)(dstB + s * 512), 16, 0, 0);

        // ---- A: regular loads -> split in VGPR -> ds_write_b128 ----
        floatx4 f0[4], f1[4];
#pragma unroll
        for (int s = 0; s < 4; ++s) {
            const float* p = gA + (size_t)(s * 16) * D_K + kbase;
            f0[s] = *(const floatx4*)p;
            f1[s] = *(const floatx4*)(p + 4);
        }
#pragma unroll
        for (int s = 0; s < 4; ++s) {
            uint4v hi, lo;
            split_chunk(f0[s], f1[s], &hi, &lo);
            const int off = (wave * 4 + s) * 512 + wroff;
            *(uint4v*)(sAh + off) = hi;
            *(uint4v*)(sAl + off) = lo;
        }
        __syncthreads();

        // ---- fragments (swizzle-matched, conflict-free) + 3-term MFMA ----
        bf16x8 ah[4], al[4];
#pragma unroll
        for (int i = 0; i < 4; ++i) {
            const int aoff = (wave * 4 + i) * 512 + fragoff;
            ah[i] = *(const bf16x8*)(sAh + aoff);
            al[i] = *(const bf16x8*)(sAl + aoff);
        }
#pragma unroll
        for (int j = 0; j < 8; ++j) {
            const int boff = j * 512 + fragoff;
            bf16x8 bhj = *(const bf16x8*)(sBh + boff);
            bf16x8 blj = *(const bf16x8*)(sBl + boff);
#pragma unroll
            for (int i = 0; i < 4; ++i) {
                acc[i][j] = __builtin_amdgcn_mfma_f32_16x16x32_bf16(ah[i], bhj, acc[i][j], 0, 0, 0);
                acc[i][j] = __builtin_amdgcn_mfma_f32_16x16x32_bf16(ah[i], blj, acc[i][j], 0, 0, 0);
                acc[i][j] = __builtin_amdgcn_mfma_f32_16x16x32_bf16(al[i], bhj, acc[i][j], 0, 0, 0);
            }
        }
        __syncthreads();
    }

    // ---- epilogue: logits = 2*qp - p2[col] ----
    // C layout (verified m89/m91): col = lane&15, row = (lane>>4)*4 + reg
#pragma unroll
    for (int j = 0; j < 8; ++j) {
        const int gc = col0 + j * 16 + rsel;
        const float p2v = p2[gc];
#pragma unroll
        for (int i = 0; i < 4; ++i) {
            const int gr = row0 + wave * 64 + i * 16 + kq * 4;
#pragma unroll
            for (int r = 0; r < 4; ++r) {
                out[(size_t)(gr + r) * M_P + gc] = 2.0f * acc[i][j][r] - p2v;
            }
        }
    }
}

// ---------------------------------------------------------------------------
// Fallback (tiny workspace): naive fp32 logits + separate softmax.
// ---------------------------------------------------------------------------
__global__ __launch_bounds__(256) void naive_logits_kernel(
    const float* __restrict__ query, const float* __restrict__ proto,
    float* __restrict__ out) {
    __shared__ float qs[D_K];
    int n = blockIdx.x;
    int t = threadIdx.x;
    ((float4*)qs)[t] = ((const float4*)(query + (size_t)n * D_K))[t];
    __syncthreads();
    float acc[4] = {0.f, 0.f, 0.f, 0.f};
    float pp[4] = {0.f, 0.f, 0.f, 0.f};
    for (int d = 0; d < D_K; d += 4) {
        float4 qv = *(const float4*)(qs + d);
#pragma unroll
        for (int j = 0; j < 4; ++j) {
            const float4 pv = *(const float4*)(proto + (size_t)(t + 256 * j) * D_K + d);
            acc[j] += qv.x * pv.x + qv.y * pv.y + qv.z * pv.z + qv.w * pv.w;
            pp[j] += pv.x * pv.x + pv.y * pv.y + pv.z * pv.z + pv.w * pv.w;
        }
    }
#pragma unroll
    for (int j = 0; j < 4; ++j)
        out[(size_t)n * M_P + t + 256 * j] = 2.0f * acc[j] - pp[j];
}

// ---------------------------------------------------------------------------
// In-place row softmax, wave-per-row (no LDS/barriers). ~24 us measured.
// ---------------------------------------------------------------------------
__global__ __launch_bounds__(256) void softmax_kernel(float* __restrict__ out) {
    const int lane = threadIdx.x & 63;
    int n = blockIdx.x * 4 + (threadIdx.x >> 6);
    for (int it = 0; it < 2; ++it, n += 8192) {
        float* row = out + (size_t)n * M_P;
        floatx4 v[4];
#pragma unroll
        for (int k = 0; k < 4; ++k)
            v[k] = *((const floatx4*)row + k * 64 + lane);
        float mx = fmaxf(fmaxf(v[0].x, v[0].y), fmaxf(v[0].z, v[0].w));
#pragma unroll
        for (int k = 1; k < 4; ++k)
            mx = fmaxf(mx, fmaxf(fmaxf(v[k].x, v[k].y), fmaxf(v[k].z, v[k].w)));
#pragma unroll
        for (int off = 1; off < 64; off <<= 1) mx = fmaxf(mx, __shfl_xor(mx, off));
        float s = 0.0f;
#pragma unroll
        for (int k = 0; k < 4; ++k) {
            v[k].x = __expf(v[k].x - mx);
            v[k].y = __expf(v[k].y - mx);
            v[k].z = __expf(v[k].z - mx);
            v[k].w = __expf(v[k].w - mx);
            s += v[k].x + v[k].y + v[k].z + v[k].w;
        }
#pragma unroll
        for (int off = 1; off < 64; off <<= 1) s += __shfl_xor(s, off);
        const float inv = 1.0f / s;
#pragma unroll
        for (int k = 0; k < 4; ++k) {
            floatx4 o;
            o.x = v[k].x * inv; o.y = v[k].y * inv;
            o.z = v[k].z * inv; o.w = v[k].w * inv;
            __builtin_nontemporal_store(o, (floatx4*)row + k * 64 + lane);
        }
    }
}

extern "C" void kernel_launch(void* const* d_in, const int* in_sizes, int n_in,
                              void* d_out, int out_size, void* d_ws, size_t ws_size,
                              hipStream_t stream) {
    const float* query = (const float*)d_in[0];
    const float* proto = (const float*)d_in[1];
    float* out = (float*)d_out;

    const size_t pElems = (size_t)M_P * D_K;   // 1M
    const size_t needed = pElems * 2 * 2 + M_P * 4;  // ~4.2 MiB

    if (ws_size >= needed) {
        unsigned short* ph = (unsigned short*)d_ws;
        unsigned short* pl = ph + pElems;
        float* p2 = (float*)(pl + pElems);

        convert_proto_kernel<<<M_P, 256, 0, stream>>>(proto, ph, pl, p2);
        gemm_logits_kernel<<<(N_Q / 128) * (M_P / 128), 128, 0, stream>>>(
            query, ph, pl, p2, out);
    } else {
        naive_logits_kernel<<<N_Q, 256, 0, stream>>>(query, proto, out);
    }
    softmax_kernel<<<2048, 256, 0, stream>>>(out);
}